// Round 16
// baseline (161.239 us; speedup 1.0000x reference)
//
#include <hip/hip_runtime.h>

#define NF 128
#define FB 128           // hist/fill partition chunks
#define CB 64            // cast blocks
#define BPB 32           // bins per scan block
#define MAXNODE 10240    // LDS cursor capacity (ints)

__device__ __forceinline__ unsigned short f2bf(float f) {  // RNE bf16
    unsigned int u = __float_as_uint(f);
    unsigned int r = u + 0x7FFFu + ((u >> 16) & 1u);
    return (unsigned short)(r >> 16);
}

// ---- power iteration (blocks 0,1) + node histogram (2..FB+1) + x->bf16 cast (rest) ----
__global__ __launch_bounds__(512) void power_hist_kernel(
    const float* __restrict__ W1, const float* __restrict__ u1,
    const float* __restrict__ W2, const float* __restrict__ u2,
    const int* __restrict__ dst, int n_edges,
    int* __restrict__ hist2d, int nbin,
    const float* __restrict__ x, unsigned short* __restrict__ xb, int n_x4,
    float* __restrict__ inv_sigma, float* __restrict__ W1t,
    float* __restrict__ colzero, int* __restrict__ cnts) {
    __shared__ float Wl[128][129];
    __shared__ float us[128], vv[128], part[4][128], red[128];
    __shared__ int hist[MAXNODE];
    int tid = threadIdx.x;

    if (blockIdx.x >= 2 + FB) {  // cast x -> bf16 (RNE)
        int cb = blockIdx.x - 2 - FB;
        const float4* x4 = (const float4*)x;
        ushort4* xb4 = (ushort4*)xb;
        for (int i = cb * 512 + tid; i < n_x4; i += CB * 512) {
            float4 v = x4[i];
            ushort4 o;
            o.x = f2bf(v.x); o.y = f2bf(v.y); o.z = f2bf(v.z); o.w = f2bf(v.w);
            xb4[i] = o;
        }
        return;
    }
    if (blockIdx.x >= 2) {  // histogram chunk
        int fb = blockIdx.x - 2;
        for (int i = tid; i < nbin; i += 512) hist[i] = 0;
        __syncthreads();
        int chunk = (n_edges + FB - 1) / FB;
        int e0 = fb * chunk, e1 = min(e0 + chunk, n_edges);
        int a0 = min(e1, (e0 + 3) & ~3);
        for (int e = e0 + tid; e < a0; e += 512) atomicAdd(&hist[dst[e]], 1);
        const int4* d4 = (const int4*)dst;
        int vs = a0 >> 2, ve = e1 >> 2;
        for (int i = vs + tid; i < ve; i += 512) {
            int4 d = d4[i];
            atomicAdd(&hist[d.x], 1);
            atomicAdd(&hist[d.y], 1);
            atomicAdd(&hist[d.z], 1);
            atomicAdd(&hist[d.w], 1);
        }
        for (int e = (ve << 2) + tid; e < e1; e += 512)
            if (e >= a0) atomicAdd(&hist[dst[e]], 1);
        __syncthreads();
        for (int i = tid; i < nbin; i += 512) hist2d[(size_t)fb * nbin + i] = hist[i];
        return;
    }

    const float* W = blockIdx.x ? W2 : W1;
    const float* u = blockIdx.x ? u2 : u1;
    const float4* W4 = (const float4*)W;
    for (int j = tid; j < 4096; j += 512) {
        float4 w = W4[j];
        int r = j >> 5, c0 = (j & 31) << 2;
        Wl[r][c0] = w.x; Wl[r][c0 + 1] = w.y; Wl[r][c0 + 2] = w.z; Wl[r][c0 + 3] = w.w;
    }
    if (tid < 128) us[tid] = u[tid];
    if (blockIdx.x == 0 && tid >= 256 && tid < 512) colzero[tid - 256] = 0.f;
    if (blockIdx.x == 0 && tid < 2) cnts[tid] = 0;
    __syncthreads();

    int c = tid & 127, sl = tid >> 7;
    float acc = 0.f;
#pragma unroll
    for (int j = 0; j < 32; ++j) acc = fmaf(Wl[sl * 32 + j][c], us[sl * 32 + j], acc);
    part[sl][c] = acc;
    __syncthreads();
    if (tid < 128) {
        float v = part[0][tid] + part[1][tid] + part[2][tid] + part[3][tid];
        vv[tid] = v;
        red[tid] = v * v;
    }
    __syncthreads();
    for (int s = 64; s > 0; s >>= 1) { if (tid < s) red[tid] += red[tid + s]; __syncthreads(); }
    float nv = sqrtf(red[0]) + 1e-12f;
    __syncthreads();
    if (tid < 128) vv[tid] = vv[tid] / nv;
    __syncthreads();

    float t = 0.f;
#pragma unroll
    for (int k = 0; k < 32; ++k) t = fmaf(Wl[c][sl * 32 + k], vv[sl * 32 + k], t);
    part[sl][c] = t;
    __syncthreads();
    if (tid < 128) {
        float tv = part[0][tid] + part[1][tid] + part[2][tid] + part[3][tid];
        red[tid] = tv * tv;
    }
    __syncthreads();
    for (int s = 64; s > 0; s >>= 1) { if (tid < s) red[tid] += red[tid + s]; __syncthreads(); }
    float tt = red[0];
    float is = (sqrtf(tt) + 1e-12f) / tt;
    if (tid == 0) inv_sigma[blockIdx.x] = is;
    if (blockIdx.x == 0) {
        for (int idx = tid; idx < 16384; idx += 512) {
            int k = idx >> 7, j = idx & 127;
            W1t[idx] = Wl[j][k] * is;  // W1t[k][j]
        }
    }
}

// ---- scanA (LDS-tiled, 32 bins/block, conflict-free) + scanB (last block, all-in-LDS) ----
__global__ __launch_bounds__(512) void scanAB_kernel(int* __restrict__ hist2d,
                                                     int* __restrict__ binOff,
                                                     int nbin, int* __restrict__ cnt) {
    __shared__ int tile[128][BPB + 1];   // 128 fb x 32 bins (+1 pad)
    __shared__ int part[16][BPB + 1];
    __shared__ int sbuf[MAXNODE];        // scanB workspace (40 KB)
    __shared__ int wsum2[8], wexcl2[8];
    __shared__ int isLast;
    int tid = threadIdx.x;
    int bin0 = blockIdx.x * BPB;

    // stage 128(fb) x 32(bin) slab; wave = 2 rows of 32 consecutive ints -> coalesced
    for (int i = tid; i < 128 * BPB; i += 512) {
        int fb = i >> 5, b = i & (BPB - 1);
        int bin = bin0 + b;
        tile[fb][b] = (bin < nbin) ? hist2d[(size_t)fb * nbin + bin] : 0;
    }
    __syncthreads();

    // per-bin scan over fb: g = tid&31 owns bin g (lanes -> consecutive banks, conflict-free);
    // s = tid>>5 (0..15) owns fb slice [s*8, s*8+8)
    int g = tid & (BPB - 1), s = tid >> 5;
    int fb0 = s << 3;
    int partial = 0;
#pragma unroll
    for (int f = 0; f < 8; ++f) partial += tile[fb0 + f][g];
    part[s][g] = partial;
    __syncthreads();
    int excl = 0;
#pragma unroll
    for (int t = 0; t < 16; ++t)
        if (t < s) excl += part[t][g];
    int run = excl;
#pragma unroll
    for (int f = 0; f < 8; ++f) {
        int v = tile[fb0 + f][g];
        tile[fb0 + f][g] = run;
        run += v;
    }
    if (s == 15 && bin0 + g < nbin) binOff[bin0 + g] = run;  // bin total
    __syncthreads();

    // write back prefixed slab, coalesced
    for (int i = tid; i < 128 * BPB; i += 512) {
        int fb = i >> 5, b = i & (BPB - 1);
        int bin = bin0 + b;
        if (bin < nbin) hist2d[(size_t)fb * nbin + bin] = tile[fb][b];
    }

    // release: fence all stores, sync, tid0 signals
    __threadfence();
    __syncthreads();
    if (tid == 0) isLast = (atomicAdd(cnt, 1) == (int)gridDim.x - 1);
    __syncthreads();
    if (!isLast) return;
    __threadfence();  // acquire

    // scanB: all-in-LDS exclusive scan of binOff[0..nbin)
    for (int i = tid; i < nbin; i += 512) sbuf[i] = binOff[i];
    __syncthreads();
    int C = (nbin + 511) >> 9;
    int b0 = tid * C, b1 = min(b0 + C, nbin);
    int ssum = 0;
    for (int i = b0; i < b1; ++i) ssum += sbuf[i];
    int lane = tid & 63, wv = tid >> 6;
    int inc = ssum;
    for (int off = 1; off < 64; off <<= 1) {
        int t = __shfl_up(inc, off);
        if (lane >= off) inc += t;
    }
    if (lane == 63) wsum2[wv] = inc;
    __syncthreads();
    if (tid < 8) {
        int e2 = 0;
        for (int t = 0; t < 8; ++t)
            if (t < tid) e2 += wsum2[t];
        wexcl2[tid] = e2;
    }
    __syncthreads();
    int base = inc - ssum + wexcl2[wv];
    int run2 = base;
    for (int i = b0; i < b1; ++i) {
        int v = sbuf[i];
        sbuf[i] = run2;
        run2 += v;
    }
    __syncthreads();
    for (int i = tid; i < nbin; i += 512) binOff[i] = sbuf[i];
    if (tid == 511) binOff[nbin] = wexcl2[7] + wsum2[7];
}

// ---- fill: LDS cursors, scatter src ids into node buckets ----
__global__ __launch_bounds__(512) void fill_kernel(
    const int* __restrict__ src, const int* __restrict__ dst,
    const int* __restrict__ hist2d, const int* __restrict__ binOff,
    int* __restrict__ bucket, int nbin, int n_edges) {
    __shared__ int cur[MAXNODE];
    int tid = threadIdx.x, fb = blockIdx.x;
    for (int i = tid; i < nbin; i += 512)
        cur[i] = hist2d[(size_t)fb * nbin + i] + binOff[i];
    __syncthreads();
    int chunk = (n_edges + FB - 1) / FB;
    int e0 = fb * chunk, e1 = min(e0 + chunk, n_edges);
    int a0 = min(e1, (e0 + 3) & ~3);
    for (int e = e0 + tid; e < a0; e += 512) {
        int pos = atomicAdd(&cur[dst[e]], 1);
        bucket[pos] = src[e];
    }
    const int4* d4 = (const int4*)dst;
    const int4* s4 = (const int4*)src;
    int vs = a0 >> 2, ve = e1 >> 2;
    for (int i = vs + tid; i < ve; i += 512) {
        int4 d = d4[i];
        int4 s = s4[i];
        int p0 = atomicAdd(&cur[d.x], 1);
        int p1 = atomicAdd(&cur[d.y], 1);
        int p2 = atomicAdd(&cur[d.z], 1);
        int p3 = atomicAdd(&cur[d.w], 1);
        bucket[p0] = s.x; bucket[p1] = s.y; bucket[p2] = s.z; bucket[p3] = s.w;
    }
    for (int e = (ve << 2) + tid; e < e1; e += 512)
        if (e >= a0) {
            int pos = atomicAdd(&cur[dst[e]], 1);
            bucket[pos] = src[e];
        }
}

// ---- gather (bf16 source): wave-per-node, 8-edge ILP; h0 = x + sum x[src] (f32 acc) ----
__global__ __launch_bounds__(256) void gather_kernel(
    const unsigned short* __restrict__ xb, const int* __restrict__ bucket,
    const int* __restrict__ binOff, float* __restrict__ h0, int n_nodes) {
    int gw = (blockIdx.x * blockDim.x + threadIdx.x) >> 6;
    int lane = threadIdx.x & 63;
    if (gw >= n_nodes) return;
    const unsigned int* xu = (const unsigned int*)xb;
    unsigned int u0 = xu[(size_t)gw * 64 + lane];
    float2 acc;
    acc.x = __uint_as_float(u0 << 16);
    acc.y = __uint_as_float(u0 & 0xFFFF0000u);
    int j = binOff[gw], end = binOff[gw + 1];
    for (; j + 8 <= end; j += 8) {
        int s0 = bucket[j],     s1 = bucket[j + 1], s2 = bucket[j + 2], s3 = bucket[j + 3];
        int s4 = bucket[j + 4], s5 = bucket[j + 5], s6 = bucket[j + 6], s7 = bucket[j + 7];
        unsigned int v0 = xu[(size_t)s0 * 64 + lane];
        unsigned int v1 = xu[(size_t)s1 * 64 + lane];
        unsigned int v2 = xu[(size_t)s2 * 64 + lane];
        unsigned int v3 = xu[(size_t)s3 * 64 + lane];
        unsigned int v4 = xu[(size_t)s4 * 64 + lane];
        unsigned int v5 = xu[(size_t)s5 * 64 + lane];
        unsigned int v6 = xu[(size_t)s6 * 64 + lane];
        unsigned int v7 = xu[(size_t)s7 * 64 + lane];
        acc.x += __uint_as_float(v0 << 16) + __uint_as_float(v1 << 16)
               + __uint_as_float(v2 << 16) + __uint_as_float(v3 << 16)
               + __uint_as_float(v4 << 16) + __uint_as_float(v5 << 16)
               + __uint_as_float(v6 << 16) + __uint_as_float(v7 << 16);
        acc.y += __uint_as_float(v0 & 0xFFFF0000u) + __uint_as_float(v1 & 0xFFFF0000u)
               + __uint_as_float(v2 & 0xFFFF0000u) + __uint_as_float(v3 & 0xFFFF0000u)
               + __uint_as_float(v4 & 0xFFFF0000u) + __uint_as_float(v5 & 0xFFFF0000u)
               + __uint_as_float(v6 & 0xFFFF0000u) + __uint_as_float(v7 & 0xFFFF0000u);
    }
    for (; j < end; ++j) {
        unsigned int v = xu[(size_t)bucket[j] * 64 + lane];
        acc.x += __uint_as_float(v << 16);
        acc.y += __uint_as_float(v & 0xFFFF0000u);
    }
    ((float2*)h0)[(size_t)gw * 64 + lane] = acc;
}

// ---- fallback: atomic scatter (f32) ----
__global__ void edge_scatter_kernel(const int* __restrict__ ei, const float* __restrict__ x,
                                    float* __restrict__ h0, int n_edges) {
    int gtid = blockIdx.x * blockDim.x + threadIdx.x;
    int wid = gtid >> 6;
    int lane = threadIdx.x & 63;
    int nw = (gridDim.x * blockDim.x) >> 6;
    const int* srcs = ei;
    const int* dsts = ei + n_edges;
    for (int e = wid; e < n_edges; e += nw) {
        int s = srcs[e];
        int d = dsts[e];
        atomicAdd(&h0[d * NF + lane], x[s * NF + lane]);
        atomicAdd(&h0[d * NF + 64 + lane], x[s * NF + 64 + lane]);
    }
}

// ---- GEMM BM=16: O = act(H @ Wt + bias); ~625 blocks for occupancy ----
template <bool RELU, bool BNACC>
__global__ __launch_bounds__(256, 4) void gemm16_kernel(
    const float* __restrict__ H, const float* __restrict__ Wt,
    const float* __restrict__ bias, float* __restrict__ O,
    float* __restrict__ colsum, float* __restrict__ colsumsq, int n_rows) {
    __shared__ float Hl[16][128];  // 8 KB
    int tid = threadIdx.x;
    int m0 = blockIdx.x * 16;

    const float4* H4 = (const float4*)H;
    for (int j = tid; j < 512; j += 256) {
        int r = j >> 5, k4 = j & 31;
        int gr = m0 + r;
        float4 h = (gr < n_rows) ? H4[(size_t)gr * 32 + k4] : make_float4(0.f, 0.f, 0.f, 0.f);
        *(float4*)&Hl[r][k4 << 2] = h;
    }
    __syncthreads();

    int tx = tid & 31, ty = tid >> 5;  // ty 0..7
    int rb = ty * 2, cb = tx * 4;
    float acc[2][4] = {};
    const float4* Wt4 = (const float4*)Wt;

#pragma unroll 2
    for (int k = 0; k < 128; k += 4) {
        float4 w0 = Wt4[(k + 0) * 32 + tx];
        float4 w1 = Wt4[(k + 1) * 32 + tx];
        float4 w2 = Wt4[(k + 2) * 32 + tx];
        float4 w3 = Wt4[(k + 3) * 32 + tx];
        float wv[4][4] = {{w0.x, w0.y, w0.z, w0.w}, {w1.x, w1.y, w1.z, w1.w},
                          {w2.x, w2.y, w2.z, w2.w}, {w3.x, w3.y, w3.z, w3.w}};
#pragma unroll
        for (int i = 0; i < 2; ++i) {
            float4 h = *(const float4*)&Hl[rb + i][k];
            float hf[4] = {h.x, h.y, h.z, h.w};
#pragma unroll
            for (int kk = 0; kk < 4; ++kk)
#pragma unroll
                for (int j = 0; j < 4; ++j)
                    acc[i][j] = fmaf(hf[kk], wv[kk][j], acc[i][j]);
        }
    }

    float bv[4];
#pragma unroll
    for (int j = 0; j < 4; ++j) bv[j] = bias[cb + j];

    float s[4] = {0.f, 0.f, 0.f, 0.f}, q[4] = {0.f, 0.f, 0.f, 0.f};
#pragma unroll
    for (int i = 0; i < 2; ++i) {
        int gr = m0 + rb + i;
        if (gr < n_rows) {
            float o[4];
#pragma unroll
            for (int j = 0; j < 4; ++j) {
                float v = acc[i][j] + bv[j];
                if (RELU) v = fmaxf(v, 0.f);
                o[j] = v;
                if (BNACC) { s[j] += v; q[j] = fmaf(v, v, q[j]); }
            }
            *(float4*)&O[(size_t)gr * NF + cb] = make_float4(o[0], o[1], o[2], o[3]);
        }
    }

    if (BNACC) {
        __syncthreads();
        float* sS = &Hl[0][0];
        float* sQ = &Hl[8][0];
#pragma unroll
        for (int j = 0; j < 4; ++j) {
            sS[ty * 128 + cb + j] = s[j];
            sQ[ty * 128 + cb + j] = q[j];
        }
        __syncthreads();
        if (tid < 128) {
            float ts = 0.f, tq = 0.f;
#pragma unroll
            for (int g = 0; g < 8; ++g) {
                ts += sS[g * 128 + tid];
                tq += sQ[g * 128 + tid];
            }
            atomicAdd(&colsum[tid], ts);
            atomicAdd(&colsumsq[tid], tq);
        }
    }
}

// ---- fold BN into W2', emit TRANSPOSED W2pt[k][j], b2p (separate, 128 blocks) ----
__global__ void fold_kernel(const float* __restrict__ W2, const float* __restrict__ b2,
                            const float* __restrict__ gamma, const float* __restrict__ beta,
                            const float* __restrict__ colsum, const float* __restrict__ colsumsq,
                            const float* __restrict__ inv_sigma, float* __restrict__ W2pt,
                            float* __restrict__ b2p, float inv_n) {
    __shared__ float a[128], cc[128], red[128];
    int k = threadIdx.x;
    int j = blockIdx.x;
    float mu = colsum[k] * inv_n;
    float var = colsumsq[k] * inv_n - mu * mu;
    float ai = gamma[k] / sqrtf(var + 1e-5f);
    a[k] = ai;
    cc[k] = beta[k] - ai * mu;
    __syncthreads();
    float is2 = inv_sigma[1];
    float wv = W2[j * 128 + k] * is2;
    W2pt[k * 128 + j] = wv * a[k];
    red[k] = wv * cc[k];
    __syncthreads();
    for (int s = 64; s > 0; s >>= 1) { if (k < s) red[k] += red[k + s]; __syncthreads(); }
    if (k == 0) b2p[j] = b2[j] + red[0];
}

extern "C" void kernel_launch(void* const* d_in, const int* in_sizes, int n_in,
                              void* d_out, int out_size, void* d_ws, size_t ws_size,
                              hipStream_t stream) {
    const float* x     = (const float*)d_in[0];
    const int*   ei    = (const int*)d_in[1];
    const float* W1    = (const float*)d_in[2];
    const float* b1    = (const float*)d_in[3];
    const float* u1    = (const float*)d_in[4];
    const float* gamma = (const float*)d_in[5];
    const float* beta  = (const float*)d_in[6];
    const float* W2    = (const float*)d_in[7];
    const float* b2    = (const float*)d_in[8];
    const float* u2    = (const float*)d_in[9];
    float* out = (float*)d_out;

    int n_nodes = in_sizes[0] / NF;
    int n_edges = in_sizes[1] / 2;
    int nbin = n_nodes;
    int nbin_pad = (nbin + 1 + 3) & ~3;
    int nedge_pad = (n_edges + 3) & ~3;
    size_t scratch = (size_t)FB * nbin > (size_t)n_nodes * NF
                   ? (size_t)FB * nbin : (size_t)n_nodes * NF;
    scratch = (scratch + 3) & ~(size_t)3;

    float* ws        = (float*)d_ws;
    float* inv_sigma = ws;                     // 4
    float* colsum    = ws + 4;                 // 128
    float* colsumsq  = colsum + 128;           // 128
    float* W1t       = colsumsq + 128;         // 16384
    float* W2pt      = W1t + 16384;            // 16384
    float* b2p       = W2pt + 16384;           // 128  (33156 floats)
    int*   cnts      = (int*)(b2p + 128);      // 4 ints
    int*   binOff    = cnts + 4;               // nbin_pad
    int*   bucket    = binOff + nbin_pad;      // nedge_pad
    int*   hist2d    = bucket + nedge_pad;     // scratch (fallback h0 alias)
    float* h0        = (float*)hist2d;
    unsigned short* xb = (unsigned short*)(hist2d + scratch);   // n_nodes*128 bf16
    float* h0g       = (float*)(xb + (size_t)n_nodes * NF);     // n_nodes*128 f32

    size_t need = (size_t)(33160 + nbin_pad + nedge_pad + scratch) * 4
                + (size_t)n_nodes * NF * 2 + (size_t)n_nodes * NF * 4;
    bool fused = (n_nodes <= MAXNODE) && (ws_size >= need);

    int n_x4 = n_nodes * 32;
    int gemm_blocks = (n_nodes + 15) / 16;

    if (fused) {
        // K1: power iter (zeros colsum+cnts, emits W1t) + node hist + bf16 cast
        power_hist_kernel<<<2 + FB + CB, 512, 0, stream>>>(
            W1, u1, W2, u2, ei + n_edges, n_edges, hist2d, nbin,
            x, xb, n_x4, inv_sigma, W1t, colsum, cnts);
        // K2: conflict-free LDS scanA (313 blocks) + all-in-LDS scanB (last block)
        scanAB_kernel<<<(nbin + BPB - 1) / BPB, 512, 0, stream>>>(hist2d, binOff, nbin,
                                                                  &cnts[0]);
        // K3: fill buckets
        fill_kernel<<<FB, 512, 0, stream>>>(ei, ei + n_edges, hist2d, binOff, bucket,
                                            nbin, n_edges);
        // K4: gather (wave-per-node, full-GPU TLP) -> h0g
        gather_kernel<<<(n_nodes * 64 + 255) / 256, 256, 0, stream>>>(
            xb, bucket, binOff, h0g, n_nodes);
        // K5: gemm1 + ReLU + BN stats (625 blocks)
        gemm16_kernel<true, true><<<gemm_blocks, 256, 0, stream>>>(
            h0g, W1t, b1, out, colsum, colsumsq, n_nodes);
    } else {
        power_hist_kernel<<<2, 512, 0, stream>>>(
            W1, u1, W2, u2, ei + n_edges, n_edges, hist2d, nbin,
            x, xb, 0, inv_sigma, W1t, colsum, cnts);
        hipMemcpyAsync(h0, x, (size_t)n_nodes * NF * sizeof(float),
                       hipMemcpyDeviceToDevice, stream);
        edge_scatter_kernel<<<2048, 256, 0, stream>>>(ei, x, h0, n_edges);
        gemm16_kernel<true, true><<<gemm_blocks, 256, 0, stream>>>(
            h0, W1t, b1, out, colsum, colsumsq, n_nodes);
    }

    // K6: BN fold -> W2pt, b2p (128 blocks, ~4 µs)
    fold_kernel<<<128, 128, 0, stream>>>(W2, b2, gamma, beta, colsum, colsumsq,
                                         inv_sigma, W2pt, b2p, 1.0f / (float)n_nodes);

    // K7: out = h1 @ W2pt + b2p (in-place: block stages its own 16 rows first)
    gemm16_kernel<false, false><<<gemm_blocks, 256, 0, stream>>>(
        out, W2pt, b2p, out, nullptr, nullptr, n_nodes);
}

// Round 17
// 123.641 us; speedup vs baseline: 1.3041x; 1.3041x over previous
//
#include <hip/hip_runtime.h>

#define NF 128
#define FB 128           // hist/fill partition chunks
#define CB 64            // cast blocks
#define BPB 128          // bins per scan block (4 threads/bin)
#define MAXNODE 10240    // LDS cursor capacity (ints)

__device__ __forceinline__ unsigned short f2bf(float f) {  // RNE bf16
    unsigned int u = __float_as_uint(f);
    unsigned int r = u + 0x7FFFu + ((u >> 16) & 1u);
    return (unsigned short)(r >> 16);
}

// ---- power iteration (blocks 0,1) + node histogram (2..FB+1) + x->bf16 cast (rest) ----
__global__ __launch_bounds__(512) void power_hist_kernel(
    const float* __restrict__ W1, const float* __restrict__ u1,
    const float* __restrict__ W2, const float* __restrict__ u2,
    const int* __restrict__ dst, int n_edges,
    int* __restrict__ hist2d, int nbin,
    const float* __restrict__ x, unsigned short* __restrict__ xb, int n_x4,
    float* __restrict__ inv_sigma, float* __restrict__ W1t,
    float* __restrict__ colzero, int* __restrict__ cnts) {
    __shared__ float Wl[128][129];
    __shared__ float us[128], vv[128], part[4][128], red[128];
    __shared__ int hist[MAXNODE];
    int tid = threadIdx.x;

    if (blockIdx.x >= 2 + FB) {  // cast x -> bf16 (RNE)
        int cb = blockIdx.x - 2 - FB;
        const float4* x4 = (const float4*)x;
        ushort4* xb4 = (ushort4*)xb;
        for (int i = cb * 512 + tid; i < n_x4; i += CB * 512) {
            float4 v = x4[i];
            ushort4 o;
            o.x = f2bf(v.x); o.y = f2bf(v.y); o.z = f2bf(v.z); o.w = f2bf(v.w);
            xb4[i] = o;
        }
        return;
    }
    if (blockIdx.x >= 2) {  // histogram chunk
        int fb = blockIdx.x - 2;
        for (int i = tid; i < nbin; i += 512) hist[i] = 0;
        __syncthreads();
        int chunk = (n_edges + FB - 1) / FB;
        int e0 = fb * chunk, e1 = min(e0 + chunk, n_edges);
        int a0 = min(e1, (e0 + 3) & ~3);
        for (int e = e0 + tid; e < a0; e += 512) atomicAdd(&hist[dst[e]], 1);
        const int4* d4 = (const int4*)dst;
        int vs = a0 >> 2, ve = e1 >> 2;
        for (int i = vs + tid; i < ve; i += 512) {
            int4 d = d4[i];
            atomicAdd(&hist[d.x], 1);
            atomicAdd(&hist[d.y], 1);
            atomicAdd(&hist[d.z], 1);
            atomicAdd(&hist[d.w], 1);
        }
        for (int e = (ve << 2) + tid; e < e1; e += 512)
            if (e >= a0) atomicAdd(&hist[dst[e]], 1);
        __syncthreads();
        for (int i = tid; i < nbin; i += 512) hist2d[(size_t)fb * nbin + i] = hist[i];
        return;
    }

    const float* W = blockIdx.x ? W2 : W1;
    const float* u = blockIdx.x ? u2 : u1;
    const float4* W4 = (const float4*)W;
    for (int j = tid; j < 4096; j += 512) {
        float4 w = W4[j];
        int r = j >> 5, c0 = (j & 31) << 2;
        Wl[r][c0] = w.x; Wl[r][c0 + 1] = w.y; Wl[r][c0 + 2] = w.z; Wl[r][c0 + 3] = w.w;
    }
    if (tid < 128) us[tid] = u[tid];
    if (blockIdx.x == 0 && tid >= 256 && tid < 512) colzero[tid - 256] = 0.f;
    if (blockIdx.x == 0 && tid < 2) cnts[tid] = 0;
    __syncthreads();

    int c = tid & 127, sl = tid >> 7;
    float acc = 0.f;
#pragma unroll
    for (int j = 0; j < 32; ++j) acc = fmaf(Wl[sl * 32 + j][c], us[sl * 32 + j], acc);
    part[sl][c] = acc;
    __syncthreads();
    if (tid < 128) {
        float v = part[0][tid] + part[1][tid] + part[2][tid] + part[3][tid];
        vv[tid] = v;
        red[tid] = v * v;
    }
    __syncthreads();
    for (int s = 64; s > 0; s >>= 1) { if (tid < s) red[tid] += red[tid + s]; __syncthreads(); }
    float nv = sqrtf(red[0]) + 1e-12f;
    __syncthreads();
    if (tid < 128) vv[tid] = vv[tid] / nv;
    __syncthreads();

    float t = 0.f;
#pragma unroll
    for (int k = 0; k < 32; ++k) t = fmaf(Wl[c][sl * 32 + k], vv[sl * 32 + k], t);
    part[sl][c] = t;
    __syncthreads();
    if (tid < 128) {
        float tv = part[0][tid] + part[1][tid] + part[2][tid] + part[3][tid];
        red[tid] = tv * tv;
    }
    __syncthreads();
    for (int s = 64; s > 0; s >>= 1) { if (tid < s) red[tid] += red[tid + s]; __syncthreads(); }
    float tt = red[0];
    float is = (sqrtf(tt) + 1e-12f) / tt;
    if (tid == 0) inv_sigma[blockIdx.x] = is;
    if (blockIdx.x == 0) {
        for (int idx = tid; idx < 16384; idx += 512) {
            int k = idx >> 7, j = idx & 127;
            W1t[idx] = Wl[j][k] * is;  // W1t[k][j]
        }
    }
}

// ---- scanA: register-staged, 4 thr/bin x 32 fb each (ILP-32) + scanB (last block) ----
__global__ __launch_bounds__(512) void scanAB_kernel(int* __restrict__ hist2d,
                                                     int* __restrict__ binOff,
                                                     int nbin, int* __restrict__ cnt) {
    __shared__ int part[4][132];
    __shared__ int sbuf[MAXNODE];   // scanB workspace (last block only)
    __shared__ int wsum2[8], wexcl2[8];
    __shared__ int isLast;
    int tid = threadIdx.x;
    int binrel = tid >> 2;           // 0..127
    int q = tid & 3;                 // fb quarter
    int bin = blockIdx.x * BPB + binrel;
    int fb0 = q * 32;

    int v[32];
    if (bin < nbin) {
#pragma unroll
        for (int f = 0; f < 32; ++f)
            v[f] = hist2d[(size_t)(fb0 + f) * nbin + bin];   // 32 independent loads
        int partial = 0;
#pragma unroll
        for (int f = 0; f < 32; ++f) partial += v[f];
        part[q][binrel] = partial;
    }
    __syncthreads();
    if (bin < nbin) {
        int run = 0;
#pragma unroll
        for (int t = 0; t < 4; ++t)
            if (t < q) run += part[t][binrel];
#pragma unroll
        for (int f = 0; f < 32; ++f) {
            hist2d[(size_t)(fb0 + f) * nbin + bin] = run;    // 32 independent stores
            run += v[f];
        }
        if (q == 3)
            binOff[bin] = part[0][binrel] + part[1][binrel] + part[2][binrel] + part[3][binrel];
    }

    // release: fence all stores, sync, tid0 signals
    __threadfence();
    __syncthreads();
    if (tid == 0) isLast = (atomicAdd(cnt, 1) == (int)gridDim.x - 1);
    __syncthreads();
    if (!isLast) return;
    __threadfence();  // acquire

    // scanB: all-in-LDS exclusive scan of binOff[0..nbin)
    for (int i = tid; i < nbin; i += 512) sbuf[i] = binOff[i];
    __syncthreads();
    int C = (nbin + 511) >> 9;
    int b0 = tid * C, b1 = min(b0 + C, nbin);
    int ssum = 0;
    for (int i = b0; i < b1; ++i) ssum += sbuf[i];
    int lane = tid & 63, wv = tid >> 6;
    int inc = ssum;
    for (int off = 1; off < 64; off <<= 1) {
        int t = __shfl_up(inc, off);
        if (lane >= off) inc += t;
    }
    if (lane == 63) wsum2[wv] = inc;
    __syncthreads();
    if (tid < 8) {
        int e2 = 0;
        for (int t = 0; t < 8; ++t)
            if (t < tid) e2 += wsum2[t];
        wexcl2[tid] = e2;
    }
    __syncthreads();
    int base = inc - ssum + wexcl2[wv];
    int run2 = base;
    for (int i = b0; i < b1; ++i) {
        int vv2 = sbuf[i];
        sbuf[i] = run2;
        run2 += vv2;
    }
    __syncthreads();
    for (int i = tid; i < nbin; i += 512) binOff[i] = sbuf[i];
    if (tid == 511) binOff[nbin] = wexcl2[7] + wsum2[7];
}

// ---- fill: LDS cursors, scatter src ids into node buckets ----
__global__ __launch_bounds__(512) void fill_kernel(
    const int* __restrict__ src, const int* __restrict__ dst,
    const int* __restrict__ hist2d, const int* __restrict__ binOff,
    int* __restrict__ bucket, int nbin, int n_edges) {
    __shared__ int cur[MAXNODE];
    int tid = threadIdx.x, fb = blockIdx.x;
    for (int i = tid; i < nbin; i += 512)
        cur[i] = hist2d[(size_t)fb * nbin + i] + binOff[i];
    __syncthreads();
    int chunk = (n_edges + FB - 1) / FB;
    int e0 = fb * chunk, e1 = min(e0 + chunk, n_edges);
    int a0 = min(e1, (e0 + 3) & ~3);
    for (int e = e0 + tid; e < a0; e += 512) {
        int pos = atomicAdd(&cur[dst[e]], 1);
        bucket[pos] = src[e];
    }
    const int4* d4 = (const int4*)dst;
    const int4* s4 = (const int4*)src;
    int vs = a0 >> 2, ve = e1 >> 2;
    for (int i = vs + tid; i < ve; i += 512) {
        int4 d = d4[i];
        int4 s = s4[i];
        int p0 = atomicAdd(&cur[d.x], 1);
        int p1 = atomicAdd(&cur[d.y], 1);
        int p2 = atomicAdd(&cur[d.z], 1);
        int p3 = atomicAdd(&cur[d.w], 1);
        bucket[p0] = s.x; bucket[p1] = s.y; bucket[p2] = s.z; bucket[p3] = s.w;
    }
    for (int e = (ve << 2) + tid; e < e1; e += 512)
        if (e >= a0) {
            int pos = atomicAdd(&cur[dst[e]], 1);
            bucket[pos] = src[e];
        }
}

// ---- gather (bf16 source): wave-per-node, 8-edge ILP; h0 = x + sum x[src] (f32 acc) ----
__global__ __launch_bounds__(256) void gather_kernel(
    const unsigned short* __restrict__ xb, const int* __restrict__ bucket,
    const int* __restrict__ binOff, float* __restrict__ h0, int n_nodes) {
    int gw = (blockIdx.x * blockDim.x + threadIdx.x) >> 6;
    int lane = threadIdx.x & 63;
    if (gw >= n_nodes) return;
    const unsigned int* xu = (const unsigned int*)xb;
    unsigned int u0 = xu[(size_t)gw * 64 + lane];
    float2 acc;
    acc.x = __uint_as_float(u0 << 16);
    acc.y = __uint_as_float(u0 & 0xFFFF0000u);
    int j = binOff[gw], end = binOff[gw + 1];
    for (; j + 8 <= end; j += 8) {
        int s0 = bucket[j],     s1 = bucket[j + 1], s2 = bucket[j + 2], s3 = bucket[j + 3];
        int s4 = bucket[j + 4], s5 = bucket[j + 5], s6 = bucket[j + 6], s7 = bucket[j + 7];
        unsigned int v0 = xu[(size_t)s0 * 64 + lane];
        unsigned int v1 = xu[(size_t)s1 * 64 + lane];
        unsigned int v2 = xu[(size_t)s2 * 64 + lane];
        unsigned int v3 = xu[(size_t)s3 * 64 + lane];
        unsigned int v4 = xu[(size_t)s4 * 64 + lane];
        unsigned int v5 = xu[(size_t)s5 * 64 + lane];
        unsigned int v6 = xu[(size_t)s6 * 64 + lane];
        unsigned int v7 = xu[(size_t)s7 * 64 + lane];
        acc.x += __uint_as_float(v0 << 16) + __uint_as_float(v1 << 16)
               + __uint_as_float(v2 << 16) + __uint_as_float(v3 << 16)
               + __uint_as_float(v4 << 16) + __uint_as_float(v5 << 16)
               + __uint_as_float(v6 << 16) + __uint_as_float(v7 << 16);
        acc.y += __uint_as_float(v0 & 0xFFFF0000u) + __uint_as_float(v1 & 0xFFFF0000u)
               + __uint_as_float(v2 & 0xFFFF0000u) + __uint_as_float(v3 & 0xFFFF0000u)
               + __uint_as_float(v4 & 0xFFFF0000u) + __uint_as_float(v5 & 0xFFFF0000u)
               + __uint_as_float(v6 & 0xFFFF0000u) + __uint_as_float(v7 & 0xFFFF0000u);
    }
    for (; j < end; ++j) {
        unsigned int v = xu[(size_t)bucket[j] * 64 + lane];
        acc.x += __uint_as_float(v << 16);
        acc.y += __uint_as_float(v & 0xFFFF0000u);
    }
    ((float2*)h0)[(size_t)gw * 64 + lane] = acc;
}

// ---- fallback: atomic scatter (f32) ----
__global__ void edge_scatter_kernel(const int* __restrict__ ei, const float* __restrict__ x,
                                    float* __restrict__ h0, int n_edges) {
    int gtid = blockIdx.x * blockDim.x + threadIdx.x;
    int wid = gtid >> 6;
    int lane = threadIdx.x & 63;
    int nw = (gridDim.x * blockDim.x) >> 6;
    const int* srcs = ei;
    const int* dsts = ei + n_edges;
    for (int e = wid; e < n_edges; e += nw) {
        int s = srcs[e];
        int d = dsts[e];
        atomicAdd(&h0[d * NF + lane], x[s * NF + lane]);
        atomicAdd(&h0[d * NF + 64 + lane], x[s * NF + 64 + lane]);
    }
}

// ---- GEMM BM=16: O = act(H @ Wt + bias); ~625 blocks for occupancy ----
template <bool RELU, bool BNACC>
__global__ __launch_bounds__(256, 4) void gemm16_kernel(
    const float* __restrict__ H, const float* __restrict__ Wt,
    const float* __restrict__ bias, float* __restrict__ O,
    float* __restrict__ colsum, float* __restrict__ colsumsq, int n_rows) {
    __shared__ float Hl[16][128];  // 8 KB
    int tid = threadIdx.x;
    int m0 = blockIdx.x * 16;

    const float4* H4 = (const float4*)H;
    for (int j = tid; j < 512; j += 256) {
        int r = j >> 5, k4 = j & 31;
        int gr = m0 + r;
        float4 h = (gr < n_rows) ? H4[(size_t)gr * 32 + k4] : make_float4(0.f, 0.f, 0.f, 0.f);
        *(float4*)&Hl[r][k4 << 2] = h;
    }
    __syncthreads();

    int tx = tid & 31, ty = tid >> 5;  // ty 0..7
    int rb = ty * 2, cb = tx * 4;
    float acc[2][4] = {};
    const float4* Wt4 = (const float4*)Wt;

#pragma unroll 2
    for (int k = 0; k < 128; k += 4) {
        float4 w0 = Wt4[(k + 0) * 32 + tx];
        float4 w1 = Wt4[(k + 1) * 32 + tx];
        float4 w2 = Wt4[(k + 2) * 32 + tx];
        float4 w3 = Wt4[(k + 3) * 32 + tx];
        float wv[4][4] = {{w0.x, w0.y, w0.z, w0.w}, {w1.x, w1.y, w1.z, w1.w},
                          {w2.x, w2.y, w2.z, w2.w}, {w3.x, w3.y, w3.z, w3.w}};
#pragma unroll
        for (int i = 0; i < 2; ++i) {
            float4 h = *(const float4*)&Hl[rb + i][k];
            float hf[4] = {h.x, h.y, h.z, h.w};
#pragma unroll
            for (int kk = 0; kk < 4; ++kk)
#pragma unroll
                for (int j = 0; j < 4; ++j)
                    acc[i][j] = fmaf(hf[kk], wv[kk][j], acc[i][j]);
        }
    }

    float bv[4];
#pragma unroll
    for (int j = 0; j < 4; ++j) bv[j] = bias[cb + j];

    float s[4] = {0.f, 0.f, 0.f, 0.f}, q[4] = {0.f, 0.f, 0.f, 0.f};
#pragma unroll
    for (int i = 0; i < 2; ++i) {
        int gr = m0 + rb + i;
        if (gr < n_rows) {
            float o[4];
#pragma unroll
            for (int j = 0; j < 4; ++j) {
                float v = acc[i][j] + bv[j];
                if (RELU) v = fmaxf(v, 0.f);
                o[j] = v;
                if (BNACC) { s[j] += v; q[j] = fmaf(v, v, q[j]); }
            }
            *(float4*)&O[(size_t)gr * NF + cb] = make_float4(o[0], o[1], o[2], o[3]);
        }
    }

    if (BNACC) {
        __syncthreads();
        float* sS = &Hl[0][0];
        float* sQ = &Hl[8][0];
#pragma unroll
        for (int j = 0; j < 4; ++j) {
            sS[ty * 128 + cb + j] = s[j];
            sQ[ty * 128 + cb + j] = q[j];
        }
        __syncthreads();
        if (tid < 128) {
            float ts = 0.f, tq = 0.f;
#pragma unroll
            for (int g = 0; g < 8; ++g) {
                ts += sS[g * 128 + tid];
                tq += sQ[g * 128 + tid];
            }
            atomicAdd(&colsum[tid], ts);
            atomicAdd(&colsumsq[tid], tq);
        }
    }
}

// ---- fold BN into W2', emit TRANSPOSED W2pt[k][j], b2p (separate, 128 blocks) ----
__global__ void fold_kernel(const float* __restrict__ W2, const float* __restrict__ b2,
                            const float* __restrict__ gamma, const float* __restrict__ beta,
                            const float* __restrict__ colsum, const float* __restrict__ colsumsq,
                            const float* __restrict__ inv_sigma, float* __restrict__ W2pt,
                            float* __restrict__ b2p, float inv_n) {
    __shared__ float a[128], cc[128], red[128];
    int k = threadIdx.x;
    int j = blockIdx.x;
    float mu = colsum[k] * inv_n;
    float var = colsumsq[k] * inv_n - mu * mu;
    float ai = gamma[k] / sqrtf(var + 1e-5f);
    a[k] = ai;
    cc[k] = beta[k] - ai * mu;
    __syncthreads();
    float is2 = inv_sigma[1];
    float wv = W2[j * 128 + k] * is2;
    W2pt[k * 128 + j] = wv * a[k];
    red[k] = wv * cc[k];
    __syncthreads();
    for (int s = 64; s > 0; s >>= 1) { if (k < s) red[k] += red[k + s]; __syncthreads(); }
    if (k == 0) b2p[j] = b2[j] + red[0];
}

extern "C" void kernel_launch(void* const* d_in, const int* in_sizes, int n_in,
                              void* d_out, int out_size, void* d_ws, size_t ws_size,
                              hipStream_t stream) {
    const float* x     = (const float*)d_in[0];
    const int*   ei    = (const int*)d_in[1];
    const float* W1    = (const float*)d_in[2];
    const float* b1    = (const float*)d_in[3];
    const float* u1    = (const float*)d_in[4];
    const float* gamma = (const float*)d_in[5];
    const float* beta  = (const float*)d_in[6];
    const float* W2    = (const float*)d_in[7];
    const float* b2    = (const float*)d_in[8];
    const float* u2    = (const float*)d_in[9];
    float* out = (float*)d_out;

    int n_nodes = in_sizes[0] / NF;
    int n_edges = in_sizes[1] / 2;
    int nbin = n_nodes;
    int nbin_pad = (nbin + 1 + 3) & ~3;
    int nedge_pad = (n_edges + 3) & ~3;
    size_t scratch = (size_t)FB * nbin > (size_t)n_nodes * NF
                   ? (size_t)FB * nbin : (size_t)n_nodes * NF;
    scratch = (scratch + 3) & ~(size_t)3;

    float* ws        = (float*)d_ws;
    float* inv_sigma = ws;                     // 4
    float* colsum    = ws + 4;                 // 128
    float* colsumsq  = colsum + 128;           // 128
    float* W1t       = colsumsq + 128;         // 16384
    float* W2pt      = W1t + 16384;            // 16384
    float* b2p       = W2pt + 16384;           // 128  (33156 floats)
    int*   cnts      = (int*)(b2p + 128);      // 4 ints
    int*   binOff    = cnts + 4;               // nbin_pad
    int*   bucket    = binOff + nbin_pad;      // nedge_pad
    int*   hist2d    = bucket + nedge_pad;     // scratch (fallback h0 alias)
    float* h0        = (float*)hist2d;
    unsigned short* xb = (unsigned short*)(hist2d + scratch);   // n_nodes*128 bf16
    float* h0g       = (float*)(xb + (size_t)n_nodes * NF);     // n_nodes*128 f32

    size_t need = (size_t)(33160 + nbin_pad + nedge_pad + scratch) * 4
                + (size_t)n_nodes * NF * 2 + (size_t)n_nodes * NF * 4;
    bool fused = (n_nodes <= MAXNODE) && (ws_size >= need);

    int n_x4 = n_nodes * 32;
    int gemm_blocks = (n_nodes + 15) / 16;

    if (fused) {
        // K1: power iter (zeros colsum+cnts, emits W1t) + node hist + bf16 cast
        power_hist_kernel<<<2 + FB + CB, 512, 0, stream>>>(
            W1, u1, W2, u2, ei + n_edges, n_edges, hist2d, nbin,
            x, xb, n_x4, inv_sigma, W1t, colsum, cnts);
        // K2: register-staged scanA (79 blocks) + all-in-LDS scanB (last block)
        scanAB_kernel<<<(nbin + BPB - 1) / BPB, 512, 0, stream>>>(hist2d, binOff, nbin,
                                                                  &cnts[0]);
        // K3: fill buckets
        fill_kernel<<<FB, 512, 0, stream>>>(ei, ei + n_edges, hist2d, binOff, bucket,
                                            nbin, n_edges);
        // K4: gather (wave-per-node, full-GPU TLP) -> h0g
        gather_kernel<<<(n_nodes * 64 + 255) / 256, 256, 0, stream>>>(
            xb, bucket, binOff, h0g, n_nodes);
        // K5: gemm1 + ReLU + BN stats (625 blocks)
        gemm16_kernel<true, true><<<gemm_blocks, 256, 0, stream>>>(
            h0g, W1t, b1, out, colsum, colsumsq, n_nodes);
    } else {
        power_hist_kernel<<<2, 512, 0, stream>>>(
            W1, u1, W2, u2, ei + n_edges, n_edges, hist2d, nbin,
            x, xb, 0, inv_sigma, W1t, colsum, cnts);
        hipMemcpyAsync(h0, x, (size_t)n_nodes * NF * sizeof(float),
                       hipMemcpyDeviceToDevice, stream);
        edge_scatter_kernel<<<2048, 256, 0, stream>>>(ei, x, h0, n_edges);
        gemm16_kernel<true, true><<<gemm_blocks, 256, 0, stream>>>(
            h0, W1t, b1, out, colsum, colsumsq, n_nodes);
    }

    // K6: BN fold -> W2pt, b2p (128 blocks, ~4 µs)
    fold_kernel<<<128, 128, 0, stream>>>(W2, b2, gamma, beta, colsum, colsumsq,
                                         inv_sigma, W2pt, b2p, 1.0f / (float)n_nodes);

    // K7: out = h1 @ W2pt + b2p (in-place: block stages its own 16 rows first)
    gemm16_kernel<false, false><<<gemm_blocks, 256, 0, stream>>>(
        out, W2pt, b2p, out, nullptr, nullptr, n_nodes);
}